// Round 7
// baseline (208.333 us; speedup 1.0000x reference)
//
#include <hip/hip_runtime.h>

// AdEx neuron simulation: B=32, T=2000, D=1024. Bitwise-exact vs JAX/XLA:CPU
// (numerics proven R3/R4/R6: XLA Cephes exp + FMA-contracted step, absmax 0.0).
//
// R7 = carried-cycle surgery. Measured: 242 cyc/step, issue 63 -> ~10 cyc per
// dependent edge (0.5 waves/SIMD, no TLP). Cut carried cycle to 21 edges:
//  - carry PRE-reset VP + spike flag s; chain runs the no-spike hypothesis;
//    spike branch (next V from V_reset) depends ONLY on prefetched i_t ->
//    fully off-chain: V_s = fma(dt, markdiv(nmC0+i), Vrst), nmC0 = RN(nC+etC).
//  - final cndmask VP' = s ? V_s : Vp_ns; cmp s' = (VP' >= Vs) feeds the NEXT
//    step's cndmask (20 edges of slack -> off the carried cycle).
//  - garbage chain values when s=true are discarded by cndmask, never
//    propagate (finite in f32: exp head saturates, no NaN source).
//  - spikes buffered in regs; 16 stores issued AFTER each 16-step block.
// All other numerics identical to R6 (rDT pow2 fold, KH exp-head fold,
// Delta_T-in-scale fold, Markstein div, fma(dt,dV,V)).

#define Bn 32
#define Tn 2000
#define Dn 1024
#define NEUR (Bn * Dn)     // 32768
#define UNR 16             // prefetch depth (2000 % 16 == 0 -> NB = 125)
#define NB (Tn / UNR)

// ---------- exp: XLA:CPU / Eigen Cephes, FMA-contracted (R3-proven) ----------
#define EXP_LOG2EF 1.44269504088896341f
#define EXP_C1 0.693359375f
#define EXP_C2 -2.12194440e-4f
#define EXP_P0 1.9875691500e-4f
#define EXP_P1 1.3981999507e-3f
#define EXP_P2 8.3334519073e-3f
#define EXP_P3 4.1665795894e-2f
#define EXP_P4 1.6666665459e-1f
#define EXP_P5 5.0000001201e-1f

__device__ __forceinline__ float ref_expf(float x) {
    #pragma clang fp contract(off)
    float fx = __builtin_floorf(__builtin_fmaf(x, EXP_LOG2EF, 0.5f));
    float xr = __builtin_fmaf(fx, -EXP_C1, x);
    xr = __builtin_fmaf(fx, -EXP_C2, xr);
    float z2 = xr * xr;
    float y = EXP_P0;
    y = __builtin_fmaf(y, xr, EXP_P1);
    y = __builtin_fmaf(y, xr, EXP_P2);
    y = __builtin_fmaf(y, xr, EXP_P3);
    y = __builtin_fmaf(y, xr, EXP_P4);
    y = __builtin_fmaf(y, xr, EXP_P5);
    y = __builtin_fmaf(y, z2, xr);
    y = y + 1.0f;
    const int n = (int)fx;
    return y * __int_as_float((n + 127) << 23);
}

// Delta_T * exp(t1/Delta_T), R6-proven folded form (x = t1*rDT exact;
// fma(t1,KH,0.5) == fma(x,LOG2EF,0.5) bitwise; Delta_T folded into scale).
__device__ __forceinline__ float et_from_t1(float t1, float rDT, float KH, int kdt) {
    #pragma clang fp contract(off)
    const float x  = t1 * rDT;
    const float fx = __builtin_floorf(__builtin_fmaf(t1, KH, 0.5f));
    float xr = __builtin_fmaf(fx, -EXP_C1, x);
    xr = __builtin_fmaf(fx, -EXP_C2, xr);
    const float z2 = xr * xr;
    float y = __builtin_fmaf(EXP_P0, xr, EXP_P1);
    y = __builtin_fmaf(y, xr, EXP_P2);
    y = __builtin_fmaf(y, xr, EXP_P3);
    y = __builtin_fmaf(y, xr, EXP_P4);
    y = __builtin_fmaf(y, xr, EXP_P5);
    y = __builtin_fmaf(y, z2, xr);
    y = y + 1.0f;
    const int nsc = (int)fx;
    return y * __int_as_float((nsc + 127 + kdt) << 23);
}

// ---------- R3-proven fallback steps (plain IEEE divides) ----------
__device__ __forceinline__ void step_simple(float& V, float i_t, float& spk_out,
                                            float E_L, float V_T, float Delta_T,
                                            float R, float tau_m, float V_spike,
                                            float V_reset, float dt) {
    #pragma clang fp contract(off)
    const float e  = ref_expf((V - V_T) / Delta_T);
    const float et = Delta_T * e;
    float nm = (-(V - E_L) + et);
    nm = nm + R * i_t;
    const float dV = nm / tau_m;
    V = __builtin_fmaf(dt, dV, V);
    spk_out = (V >= V_spike) ? 1.0f : 0.0f;
    V = (V >= V_spike) ? V_reset : V;
}

__device__ __forceinline__ void step_general(float& V, float& w, float i_t, float& spk_out,
                                             float E_L, float V_T, float Delta_T,
                                             float R, float tau_m, float tau_w,
                                             float a, float b,
                                             float V_spike, float V_reset, float dt) {
    #pragma clang fp contract(off)
    const float e  = ref_expf((V - V_T) / Delta_T);
    const float et = Delta_T * e;
    float nm = (-(V - E_L) + et);
    nm = __builtin_fmaf(-R, w, nm);
    nm = __builtin_fmaf(R, i_t, nm);
    const float dV = nm / tau_m;
    V = __builtin_fmaf(dt, dV, V);
    const float dwn = __builtin_fmaf(a, (V - E_L), -w);
    const float dw  = dwn / tau_w;
    w = __builtin_fmaf(dt, dw, w);
    spk_out = (V >= V_spike) ? 1.0f : 0.0f;
    const bool s = (V >= V_spike);
    V = s ? V_reset : V;
    w = s ? (w + b) : w;
}

// Double-buffered UNR-deep prefetch loop (fallback paths only).
#define RUN_BLOCKS(IPTR, OPTR, NBLK, ...) do {                                    \
    float bufA_[UNR], bufB_[UNR];                                                 \
    _Pragma("unroll") for (int k = 0; k < UNR; ++k) bufA_[k] = (IPTR)[k * Dn];    \
    for (int tb = 0; tb < (NBLK); tb += 2) {                                      \
        if (tb + 1 < (NBLK)) {                                                    \
            const float* pp_ = (IPTR) + (size_t)(tb + 1) * (UNR * Dn);            \
            _Pragma("unroll") for (int k = 0; k < UNR; ++k) bufB_[k] = pp_[k*Dn]; \
        }                                                                         \
        {                                                                         \
            float* oo_ = (OPTR) + (size_t)tb * (UNR * Dn);                        \
            _Pragma("unroll") for (int k = 0; k < UNR; ++k) {                     \
                const float i_t = bufA_[k];                                       \
                float* OSLOT = oo_ + (size_t)k * Dn; (void)OSLOT;                 \
                __VA_ARGS__;                                                      \
            }                                                                     \
        }                                                                         \
        if (tb + 2 < (NBLK)) {                                                    \
            const float* pp_ = (IPTR) + (size_t)(tb + 2) * (UNR * Dn);            \
            _Pragma("unroll") for (int k = 0; k < UNR; ++k) bufA_[k] = pp_[k*Dn]; \
        }                                                                         \
        if (tb + 1 < (NBLK)) {                                                    \
            float* oo_ = (OPTR) + (size_t)(tb + 1) * (UNR * Dn);                  \
            _Pragma("unroll") for (int k = 0; k < UNR; ++k) {                     \
                const float i_t = bufB_[k];                                       \
                float* OSLOT = oo_ + (size_t)k * Dn; (void)OSLOT;                 \
                __VA_ARGS__;                                                      \
            }                                                                     \
        }                                                                         \
    }                                                                             \
} while (0)

__launch_bounds__(128, 1)
__global__ void adex_kernel(const float* __restrict__ I,
                            const float* __restrict__ params,
                            float* __restrict__ out) {
    #pragma clang fp contract(off)

    const float tau_m   = params[0];
    const float E_L     = params[1];
    const float V_T     = params[2];
    const float Delta_T = params[3];
    const float R       = params[4];
    const float tau_w   = params[5];
    const float a       = params[6];
    const float b       = params[7];
    const float V_reset = params[8];
    const float V_spike = params[9];
    const float dt      = params[10];

    const int n = blockIdx.x * blockDim.x + threadIdx.x;
    if (n >= NEUR) return;
    const int bb = n >> 10;          // / Dn
    const int dd = n & (Dn - 1);     // % Dn

    const float* Ip = I   + (size_t)bb * (size_t)(Tn * Dn) + dd;
    float*       Op = out + (size_t)bb * (size_t)(Tn * Dn) + dd;

    const unsigned dtBits = __float_as_uint(Delta_T);
    const bool dtPow2 = ((dtBits & 0x7FFFFFu) == 0u) && Delta_T > 0.0f;
    const bool hot = (a == 0.0f) && (b == 0.0f) && (R == 1.0f) && dtPow2;

    if (hot) {
        const int   kdt = (int)((dtBits >> 23) & 0xFFu) - 127;
        const float rDT = 1.0f / Delta_T;            // exact pow2
        const float KH  = EXP_LOG2EF * rDT;          // exact exponent shift
        const float rTM = 1.0f / tau_m;              // RN(1/tau_m)
        // Spike-branch constants (same device ops as the live path -> bitwise):
        const float t1C  = V_reset - V_T;
        const float etC  = et_from_t1(t1C, rDT, KH, kdt);  // RN(DT*exp(xC))
        const float nC   = E_L - V_reset;
        const float nmC0 = nC + etC;                       // RN(nC + etC)

        // Carried state: VP = pre-reset voltage of previous step, s = its spike.
        // Selected true state = s ? V_reset : VP. Init: V0=E_L, no prior spike.
        float VP = E_L;
        bool  s  = false;

        float bufA[UNR], bufB[UNR], sp[UNR];
        #pragma unroll
        for (int k = 0; k < UNR; ++k) bufA[k] = Ip[k * Dn];

        #define HOT_STEP(i_t, kk) do {                                            \
            /* spike branch: depends only on i_t (off-chain) */                   \
            const float nms = nmC0 + (i_t);                                       \
            const float qs  = nms * rTM;                                          \
            const float ers = __builtin_fmaf(-tau_m, qs, nms);                    \
            const float dVs = __builtin_fmaf(ers, rTM, qs);                       \
            const float Vs_ = __builtin_fmaf(dt, dVs, V_reset);                   \
            /* no-spike chain from VP (garbage if s, discarded by select) */      \
            const float t1 = VP - V_T;                                            \
            const float x  = t1 * rDT;                                            \
            const float fx = __builtin_floorf(__builtin_fmaf(t1, KH, 0.5f));      \
            float xr = __builtin_fmaf(fx, -EXP_C1, x);                            \
            xr = __builtin_fmaf(fx, -EXP_C2, xr);                                 \
            const float z2 = xr * xr;                                             \
            float y = __builtin_fmaf(EXP_P0, xr, EXP_P1);                         \
            y = __builtin_fmaf(y, xr, EXP_P2);                                    \
            y = __builtin_fmaf(y, xr, EXP_P3);                                    \
            y = __builtin_fmaf(y, xr, EXP_P4);                                    \
            y = __builtin_fmaf(y, xr, EXP_P5);                                    \
            y = __builtin_fmaf(y, z2, xr);                                        \
            y = y + 1.0f;                                                         \
            const int   nsc = (int)fx;                                            \
            const float sc  = __int_as_float((nsc + 127 + kdt) << 23);            \
            const float et  = y * sc;                                             \
            const float nEL = E_L - VP;                                           \
            float nm = nEL + et;                                                  \
            nm = nm + (i_t);                                                      \
            const float q  = nm * rTM;                                            \
            const float er = __builtin_fmaf(-tau_m, q, nm);                       \
            const float dV = __builtin_fmaf(er, rTM, q);                          \
            const float Vns = __builtin_fmaf(dt, dV, VP);                         \
            VP = s ? Vs_ : Vns;      /* select true pre-reset V */                 \
            s  = (VP >= V_spike);    /* off-cycle: feeds NEXT select */           \
            sp[kk] = s ? 1.0f : 0.0f;                                             \
        } while (0)

        for (int tb = 0; tb < NB; tb += 2) {
            if (tb + 1 < NB) {
                const float* p = Ip + (size_t)(tb + 1) * (UNR * Dn);
                #pragma unroll
                for (int k = 0; k < UNR; ++k) bufB[k] = p[k * Dn];
            }
            {
                #pragma unroll
                for (int k = 0; k < UNR; ++k) HOT_STEP(bufA[k], k);
                float* o = Op + (size_t)tb * (UNR * Dn);
                #pragma unroll
                for (int k = 0; k < UNR; ++k) o[k * Dn] = sp[k];   // batched stores
            }
            if (tb + 2 < NB) {
                const float* p = Ip + (size_t)(tb + 2) * (UNR * Dn);
                #pragma unroll
                for (int k = 0; k < UNR; ++k) bufA[k] = p[k * Dn];
            }
            if (tb + 1 < NB) {
                #pragma unroll
                for (int k = 0; k < UNR; ++k) HOT_STEP(bufB[k], k);
                float* o = Op + (size_t)(tb + 1) * (UNR * Dn);
                #pragma unroll
                for (int k = 0; k < UNR; ++k) o[k * Dn] = sp[k];
            }
        }
        #undef HOT_STEP
        return;
    }

    // -------- fallback paths (R3-proven) --------
    float V = E_L;
    if (a == 0.0f && b == 0.0f) {
        RUN_BLOCKS(Ip, Op, NB,
            { float spk; step_simple(V, i_t, spk, E_L, V_T, Delta_T, R, tau_m,
                                     V_spike, V_reset, dt); *OSLOT = spk; });
    } else {
        float w = 0.0f;
        RUN_BLOCKS(Ip, Op, NB,
            { float spk; step_general(V, w, i_t, spk, E_L, V_T, Delta_T, R, tau_m,
                                      tau_w, a, b, V_spike, V_reset, dt); *OSLOT = spk; });
    }
}

extern "C" void kernel_launch(void* const* d_in, const int* in_sizes, int n_in,
                              void* d_out, int out_size, void* d_ws, size_t ws_size,
                              hipStream_t stream) {
    const float* I      = (const float*)d_in[0];
    const float* params = (const float*)d_in[1];
    float*       out    = (float*)d_out;

    dim3 block(128);
    dim3 grid(NEUR / 128);  // 256 blocks -> 1 per CU
    adex_kernel<<<grid, block, 0, stream>>>(I, params, out);
}

// Round 8
// 187.448 us; speedup vs baseline: 1.1114x; 1.1114x over previous
//
#include <hip/hip_runtime.h>

// AdEx neuron simulation: B=32, T=2000, D=1024. Bitwise-exact vs JAX/XLA:CPU
// (numerics proven R3/R4: XLA Cephes exp + FMA-contracted step, absmax 0.0).
//
// FINAL (R8) = revert to the R4 champion (187.7 us), the measured floor.
// Structural-floor arithmetic: wall = 2000 serial steps x 20-edge carried
// dependency chain (bitwise-irreducible: sub, fma, floor, 2 fma reduction,
// 6-fma poly, +1, *sc, +nEL, +i, 3-op Markstein div, fma, cndmask) x ~11
// cyc/edge single-wave VALU dep latency = ~240 cyc/step = ~190 us.
// Refuted alternatives: parallel-in-time (R5: post-reset phase ambiguity,
// zero hull collapse), chain cuts beyond 20 edges (R6 neutral), speculative
// spike branch (R7 regressed: +issue not hidden), ILP/TLP (wall = T x L per
// wave regardless of co-residency), non-bitwise rewrites (forbidden).

#define Bn 32
#define Tn 2000
#define Dn 1024
#define NEUR (Bn * Dn)     // 32768
#define UNR 16             // prefetch depth (2000 % 16 == 0 -> NB = 125)
#define NB (Tn / UNR)

// ---------- exp: XLA:CPU / Eigen Cephes, FMA-contracted (R3-proven) ----------
#define EXP_LOG2EF 1.44269504088896341f
#define EXP_C1 0.693359375f
#define EXP_C2 -2.12194440e-4f
#define EXP_P0 1.9875691500e-4f
#define EXP_P1 1.3981999507e-3f
#define EXP_P2 8.3334519073e-3f
#define EXP_P3 4.1665795894e-2f
#define EXP_P4 1.6666665459e-1f
#define EXP_P5 5.0000001201e-1f

__device__ __forceinline__ float ref_expf(float x) {
    #pragma clang fp contract(off)
    float fx = __builtin_floorf(__builtin_fmaf(x, EXP_LOG2EF, 0.5f));
    float xr = __builtin_fmaf(fx, -EXP_C1, x);
    xr = __builtin_fmaf(fx, -EXP_C2, xr);
    float z2 = xr * xr;
    float y = EXP_P0;
    y = __builtin_fmaf(y, xr, EXP_P1);
    y = __builtin_fmaf(y, xr, EXP_P2);
    y = __builtin_fmaf(y, xr, EXP_P3);
    y = __builtin_fmaf(y, xr, EXP_P4);
    y = __builtin_fmaf(y, xr, EXP_P5);
    y = __builtin_fmaf(y, z2, xr);
    y = y + 1.0f;
    const int n = (int)fx;
    return y * __int_as_float((n + 127) << 23);
}

// exp(x) * 2^kdt (kdt = log2(Delta_T), pow2): folds Delta_T multiply into the
// exact 2^n scale. Bitwise == Delta_T * ref_expf(x). (R4-proven)
__device__ __forceinline__ float expsc(float x, int kdt) {
    #pragma clang fp contract(off)
    float fx = __builtin_floorf(__builtin_fmaf(x, EXP_LOG2EF, 0.5f));
    float xr = __builtin_fmaf(fx, -EXP_C1, x);
    xr = __builtin_fmaf(fx, -EXP_C2, xr);
    float z2 = xr * xr;
    float y = EXP_P0;
    y = __builtin_fmaf(y, xr, EXP_P1);
    y = __builtin_fmaf(y, xr, EXP_P2);
    y = __builtin_fmaf(y, xr, EXP_P3);
    y = __builtin_fmaf(y, xr, EXP_P4);
    y = __builtin_fmaf(y, xr, EXP_P5);
    y = __builtin_fmaf(y, z2, xr);
    y = y + 1.0f;
    const int n = (int)fx;
    return y * __int_as_float((n + 127 + kdt) << 23);
}

// Markstein correctly-rounded division by loop-invariant d, r = RN(1/d)
// precomputed via one IEEE divide. q' == RN(x/d) bitwise for all normal x.
__device__ __forceinline__ float div_uniform(float x, float d, float r) {
    #pragma clang fp contract(off)
    float q = x * r;
    float e = __builtin_fmaf(-d, q, x);
    return __builtin_fmaf(e, r, q);
}

// ---------- R3-proven fallback steps (plain IEEE divides) ----------
__device__ __forceinline__ void step_simple(float& V, float i_t, float& spk_out,
                                            float E_L, float V_T, float Delta_T,
                                            float R, float tau_m, float V_spike,
                                            float V_reset, float dt) {
    #pragma clang fp contract(off)
    const float e  = ref_expf((V - V_T) / Delta_T);
    const float et = Delta_T * e;
    float nm = (-(V - E_L) + et);
    nm = nm + R * i_t;
    const float dV = nm / tau_m;
    V = __builtin_fmaf(dt, dV, V);
    spk_out = (V >= V_spike) ? 1.0f : 0.0f;
    V = (V >= V_spike) ? V_reset : V;
}

__device__ __forceinline__ void step_general(float& V, float& w, float i_t, float& spk_out,
                                             float E_L, float V_T, float Delta_T,
                                             float R, float tau_m, float tau_w,
                                             float a, float b,
                                             float V_spike, float V_reset, float dt) {
    #pragma clang fp contract(off)
    const float e  = ref_expf((V - V_T) / Delta_T);
    const float et = Delta_T * e;
    float nm = (-(V - E_L) + et);
    nm = __builtin_fmaf(-R, w, nm);
    nm = __builtin_fmaf(R, i_t, nm);
    const float dV = nm / tau_m;
    V = __builtin_fmaf(dt, dV, V);
    const float dwn = __builtin_fmaf(a, (V - E_L), -w);
    const float dw  = dwn / tau_w;
    w = __builtin_fmaf(dt, dw, w);
    spk_out = (V >= V_spike) ? 1.0f : 0.0f;
    const bool s = (V >= V_spike);
    V = s ? V_reset : V;
    w = s ? (w + b) : w;
}

__launch_bounds__(128, 1)
__global__ void adex_kernel(const float* __restrict__ I,
                            const float* __restrict__ params,
                            float* __restrict__ out) {
    #pragma clang fp contract(off)

    const float tau_m   = params[0];
    const float E_L     = params[1];
    const float V_T     = params[2];
    const float Delta_T = params[3];
    const float R       = params[4];
    const float tau_w   = params[5];
    const float a       = params[6];
    const float b       = params[7];
    const float V_reset = params[8];
    const float V_spike = params[9];
    const float dt      = params[10];

    const int n = blockIdx.x * blockDim.x + threadIdx.x;
    if (n >= NEUR) return;
    const int bb = n >> 10;          // / Dn
    const int dd = n & (Dn - 1);     // % Dn

    const float* Ip = I   + (size_t)bb * (size_t)(Tn * Dn) + dd;
    float*       Op = out + (size_t)bb * (size_t)(Tn * Dn) + dd;

    float V = E_L;
    float bufA[UNR], bufB[UNR];

    #pragma unroll
    for (int k = 0; k < UNR; ++k) bufA[k] = Ip[k * Dn];

    const unsigned dtBits = __float_as_uint(Delta_T);
    const bool dtPow2 = ((dtBits & 0x7FFFFFu) == 0u) && Delta_T > 0.0f;
    const bool hot = (a == 0.0f) && (b == 0.0f) && (R == 1.0f) && dtPow2;

    if (hot) {
        // -------- latency-optimized path (R4 champion) --------
        const int   kdt = (int)((dtBits >> 23) & 0xFFu) - 127;  // log2(Delta_T)
        const float rDT = 1.0f / Delta_T;                        // exact (pow2)
        const float rTM = 1.0f / tau_m;                          // RN(1/tau_m)
        // reset-branch constants (same formulas as the live branch)
        const float xC = (V_reset - V_T) * rDT;
        const float nC = E_L - V_reset;

        float x   = (V - V_T) * rDT;   // == (V-V_T)/Delta_T bitwise
        float nEL = E_L - V;           // == -(V-E_L) bitwise

        for (int tb = 0; tb < NB; tb += 2) {
            if (tb + 1 < NB) {
                const float* p = Ip + (size_t)(tb + 1) * (UNR * Dn);
                #pragma unroll
                for (int k = 0; k < UNR; ++k) bufB[k] = p[k * Dn];
            }
            {
                float* o = Op + (size_t)tb * (UNR * Dn);
                #pragma unroll
                for (int k = 0; k < UNR; ++k) {
                    const float et = expsc(x, kdt);             // Delta_T * exp(x)
                    float nm = nEL + et;
                    nm = nm + bufA[k];                          // R == 1
                    const float dV = div_uniform(nm, tau_m, rTM);
                    const float Vr = __builtin_fmaf(dt, dV, V);
                    const bool  s  = (Vr >= V_spike);
                    o[k * Dn] = s ? 1.0f : 0.0f;
                    const float xn = (Vr - V_T) * rDT;          // speculative
                    const float nn = E_L - Vr;                  // speculative
                    V   = s ? V_reset : Vr;
                    x   = s ? xC : xn;
                    nEL = s ? nC : nn;
                }
            }
            if (tb + 2 < NB) {
                const float* p = Ip + (size_t)(tb + 2) * (UNR * Dn);
                #pragma unroll
                for (int k = 0; k < UNR; ++k) bufA[k] = p[k * Dn];
            }
            if (tb + 1 < NB) {
                float* o = Op + (size_t)(tb + 1) * (UNR * Dn);
                #pragma unroll
                for (int k = 0; k < UNR; ++k) {
                    const float et = expsc(x, kdt);
                    float nm = nEL + et;
                    nm = nm + bufB[k];
                    const float dV = div_uniform(nm, tau_m, rTM);
                    const float Vr = __builtin_fmaf(dt, dV, V);
                    const bool  s  = (Vr >= V_spike);
                    o[k * Dn] = s ? 1.0f : 0.0f;
                    const float xn = (Vr - V_T) * rDT;
                    const float nn = E_L - Vr;
                    V   = s ? V_reset : Vr;
                    x   = s ? xC : xn;
                    nEL = s ? nC : nn;
                }
            }
        }
        return;
    }

    // -------- fallback paths (R3-proven) --------
    const bool simple = (a == 0.0f) && (b == 0.0f);

    if (simple) {
        for (int tb = 0; tb < NB; tb += 2) {
            if (tb + 1 < NB) {
                const float* p = Ip + (size_t)(tb + 1) * (UNR * Dn);
                #pragma unroll
                for (int k = 0; k < UNR; ++k) bufB[k] = p[k * Dn];
            }
            {
                float* o = Op + (size_t)tb * (UNR * Dn);
                #pragma unroll
                for (int k = 0; k < UNR; ++k) {
                    float spk;
                    step_simple(V, bufA[k], spk, E_L, V_T, Delta_T, R, tau_m,
                                V_spike, V_reset, dt);
                    o[k * Dn] = spk;
                }
            }
            if (tb + 2 < NB) {
                const float* p = Ip + (size_t)(tb + 2) * (UNR * Dn);
                #pragma unroll
                for (int k = 0; k < UNR; ++k) bufA[k] = p[k * Dn];
            }
            if (tb + 1 < NB) {
                float* o = Op + (size_t)(tb + 1) * (UNR * Dn);
                #pragma unroll
                for (int k = 0; k < UNR; ++k) {
                    float spk;
                    step_simple(V, bufB[k], spk, E_L, V_T, Delta_T, R, tau_m,
                                V_spike, V_reset, dt);
                    o[k * Dn] = spk;
                }
            }
        }
    } else {
        float w = 0.0f;
        for (int tb = 0; tb < NB; tb += 2) {
            if (tb + 1 < NB) {
                const float* p = Ip + (size_t)(tb + 1) * (UNR * Dn);
                #pragma unroll
                for (int k = 0; k < UNR; ++k) bufB[k] = p[k * Dn];
            }
            {
                float* o = Op + (size_t)tb * (UNR * Dn);
                #pragma unroll
                for (int k = 0; k < UNR; ++k) {
                    float spk;
                    step_general(V, w, bufA[k], spk, E_L, V_T, Delta_T, R, tau_m,
                                 tau_w, a, b, V_spike, V_reset, dt);
                    o[k * Dn] = spk;
                }
            }
            if (tb + 2 < NB) {
                const float* p = Ip + (size_t)(tb + 2) * (UNR * Dn);
                #pragma unroll
                for (int k = 0; k < UNR; ++k) bufA[k] = p[k * Dn];
            }
            if (tb + 1 < NB) {
                float* o = Op + (size_t)(tb + 1) * (UNR * Dn);
                #pragma unroll
                for (int k = 0; k < UNR; ++k) {
                    float spk;
                    step_general(V, w, bufB[k], spk, E_L, V_T, Delta_T, R, tau_m,
                                 tau_w, a, b, V_spike, V_reset, dt);
                    o[k * Dn] = spk;
                }
            }
        }
    }
}

extern "C" void kernel_launch(void* const* d_in, const int* in_sizes, int n_in,
                              void* d_out, int out_size, void* d_ws, size_t ws_size,
                              hipStream_t stream) {
    const float* I      = (const float*)d_in[0];
    const float* params = (const float*)d_in[1];
    float*       out    = (float*)d_out;

    dim3 block(128);
    dim3 grid(NEUR / 128);  // 256 blocks -> 1 per CU
    adex_kernel<<<grid, block, 0, stream>>>(I, params, out);
}

// Round 9
// 185.352 us; speedup vs baseline: 1.1240x; 1.0113x over previous
//
#include <hip/hip_runtime.h>

// AdEx neuron simulation: B=32, T=2000, D=1024. Bitwise-exact vs JAX/XLA:CPU
// (numerics proven R3/R4: XLA Cephes exp + FMA-contracted step, absmax 0.0).
//
// R9 = instruction diet on the R4/R8 champion (187.4 us). Mixed latency model
// (R7 regression: marginal ~3.7 cyc/instr on top of the 20-edge spine):
//  - SADDR addressing: keep pointers BLOCK-UNIFORM (bb = blockIdx>>3 is
//    uniform; only dd varies per lane). Access as uniform_ptr[dd] so the
//    compiler emits global_load v, v_dd, s[base] (scalar base bumped by SALU,
//    parallel pipe) instead of 64-bit VGPR-pair flat addressing (~4 VALU/step).
//  - nEL select dropped: nEL = E_L - V' direct (1 sub, ~14 edges of spine
//    slack; bitwise == s ? (E_L-Vrst) : (E_L-Vr), the old select operands).
// Spine unchanged (20 edges). All numerics identical to R8.

#define Bn 32
#define Tn 2000
#define Dn 1024
#define NEUR (Bn * Dn)     // 32768
#define UNR 16             // prefetch depth (2000 % 16 == 0 -> NB = 125)
#define NB (Tn / UNR)

// ---------- exp: XLA:CPU / Eigen Cephes, FMA-contracted (R3-proven) ----------
#define EXP_LOG2EF 1.44269504088896341f
#define EXP_C1 0.693359375f
#define EXP_C2 -2.12194440e-4f
#define EXP_P0 1.9875691500e-4f
#define EXP_P1 1.3981999507e-3f
#define EXP_P2 8.3334519073e-3f
#define EXP_P3 4.1665795894e-2f
#define EXP_P4 1.6666665459e-1f
#define EXP_P5 5.0000001201e-1f

__device__ __forceinline__ float ref_expf(float x) {
    #pragma clang fp contract(off)
    float fx = __builtin_floorf(__builtin_fmaf(x, EXP_LOG2EF, 0.5f));
    float xr = __builtin_fmaf(fx, -EXP_C1, x);
    xr = __builtin_fmaf(fx, -EXP_C2, xr);
    float z2 = xr * xr;
    float y = EXP_P0;
    y = __builtin_fmaf(y, xr, EXP_P1);
    y = __builtin_fmaf(y, xr, EXP_P2);
    y = __builtin_fmaf(y, xr, EXP_P3);
    y = __builtin_fmaf(y, xr, EXP_P4);
    y = __builtin_fmaf(y, xr, EXP_P5);
    y = __builtin_fmaf(y, z2, xr);
    y = y + 1.0f;
    const int n = (int)fx;
    return y * __int_as_float((n + 127) << 23);
}

// exp(x) * 2^kdt (kdt = log2(Delta_T), pow2): folds Delta_T multiply into the
// exact 2^n scale. Bitwise == Delta_T * ref_expf(x). (R4-proven)
__device__ __forceinline__ float expsc(float x, int kdt) {
    #pragma clang fp contract(off)
    float fx = __builtin_floorf(__builtin_fmaf(x, EXP_LOG2EF, 0.5f));
    float xr = __builtin_fmaf(fx, -EXP_C1, x);
    xr = __builtin_fmaf(fx, -EXP_C2, xr);
    float z2 = xr * xr;
    float y = EXP_P0;
    y = __builtin_fmaf(y, xr, EXP_P1);
    y = __builtin_fmaf(y, xr, EXP_P2);
    y = __builtin_fmaf(y, xr, EXP_P3);
    y = __builtin_fmaf(y, xr, EXP_P4);
    y = __builtin_fmaf(y, xr, EXP_P5);
    y = __builtin_fmaf(y, z2, xr);
    y = y + 1.0f;
    const int n = (int)fx;
    return y * __int_as_float((n + 127 + kdt) << 23);
}

// Markstein correctly-rounded division by loop-invariant d, r = RN(1/d)
// precomputed via one IEEE divide. q' == RN(x/d) bitwise for all normal x.
__device__ __forceinline__ float div_uniform(float x, float d, float r) {
    #pragma clang fp contract(off)
    float q = x * r;
    float e = __builtin_fmaf(-d, q, x);
    return __builtin_fmaf(e, r, q);
}

// ---------- R3-proven fallback steps (plain IEEE divides) ----------
__device__ __forceinline__ void step_simple(float& V, float i_t, float& spk_out,
                                            float E_L, float V_T, float Delta_T,
                                            float R, float tau_m, float V_spike,
                                            float V_reset, float dt) {
    #pragma clang fp contract(off)
    const float e  = ref_expf((V - V_T) / Delta_T);
    const float et = Delta_T * e;
    float nm = (-(V - E_L) + et);
    nm = nm + R * i_t;
    const float dV = nm / tau_m;
    V = __builtin_fmaf(dt, dV, V);
    spk_out = (V >= V_spike) ? 1.0f : 0.0f;
    V = (V >= V_spike) ? V_reset : V;
}

__device__ __forceinline__ void step_general(float& V, float& w, float i_t, float& spk_out,
                                             float E_L, float V_T, float Delta_T,
                                             float R, float tau_m, float tau_w,
                                             float a, float b,
                                             float V_spike, float V_reset, float dt) {
    #pragma clang fp contract(off)
    const float e  = ref_expf((V - V_T) / Delta_T);
    const float et = Delta_T * e;
    float nm = (-(V - E_L) + et);
    nm = __builtin_fmaf(-R, w, nm);
    nm = __builtin_fmaf(R, i_t, nm);
    const float dV = nm / tau_m;
    V = __builtin_fmaf(dt, dV, V);
    const float dwn = __builtin_fmaf(a, (V - E_L), -w);
    const float dw  = dwn / tau_w;
    w = __builtin_fmaf(dt, dw, w);
    spk_out = (V >= V_spike) ? 1.0f : 0.0f;
    const bool s = (V >= V_spike);
    V = s ? V_reset : V;
    w = s ? (w + b) : w;
}

__launch_bounds__(128, 1)
__global__ void adex_kernel(const float* __restrict__ I,
                            const float* __restrict__ params,
                            float* __restrict__ out) {
    #pragma clang fp contract(off)

    const float tau_m   = params[0];
    const float E_L     = params[1];
    const float V_T     = params[2];
    const float Delta_T = params[3];
    const float R       = params[4];
    const float tau_w   = params[5];
    const float a       = params[6];
    const float b       = params[7];
    const float V_reset = params[8];
    const float V_spike = params[9];
    const float dt      = params[10];

    // Block-uniform batch index (SGPR), per-lane column index (VGPR).
    // Same neuron assignment as n = blockIdx*128+tid: bb = n>>10, dd = n&1023.
    const int bb = (int)(blockIdx.x >> 3);                         // uniform
    const int dd = (int)((blockIdx.x & 7) * 128 + threadIdx.x);    // varying

    // Uniform row-base pointers: all per-access address math stays scalar;
    // the only vector component is dd (constant voffset register).
    const float* IpU = I   + (size_t)bb * (size_t)(Tn * Dn);
    float*       OpU = out + (size_t)bb * (size_t)(Tn * Dn);

    float V = E_L;
    float bufA[UNR], bufB[UNR];

    #pragma unroll
    for (int k = 0; k < UNR; ++k) bufA[k] = (IpU + (size_t)k * Dn)[dd];

    const unsigned dtBits = __float_as_uint(Delta_T);
    const bool dtPow2 = ((dtBits & 0x7FFFFFu) == 0u) && Delta_T > 0.0f;
    const bool hot = (a == 0.0f) && (b == 0.0f) && (R == 1.0f) && dtPow2;

    if (hot) {
        // -------- latency-optimized path --------
        const int   kdt = (int)((dtBits >> 23) & 0xFFu) - 127;  // log2(Delta_T)
        const float rDT = 1.0f / Delta_T;                        // exact (pow2)
        const float rTM = 1.0f / tau_m;                          // RN(1/tau_m)
        const float xC  = (V_reset - V_T) * rDT;                 // reset-branch x

        float x   = (V - V_T) * rDT;   // == (V-V_T)/Delta_T bitwise
        float nEL = E_L - V;           // == -(V-E_L) bitwise

        for (int tb = 0; tb < NB; tb += 2) {
            if (tb + 1 < NB) {
                const float* p = IpU + (size_t)(tb + 1) * (UNR * Dn);
                #pragma unroll
                for (int k = 0; k < UNR; ++k) bufB[k] = (p + (size_t)k * Dn)[dd];
            }
            {
                float* o = OpU + (size_t)tb * (UNR * Dn);
                #pragma unroll
                for (int k = 0; k < UNR; ++k) {
                    const float et = expsc(x, kdt);             // Delta_T * exp(x)
                    float nm = nEL + et;
                    nm = nm + bufA[k];                          // R == 1
                    const float dV = div_uniform(nm, tau_m, rTM);
                    const float Vr = __builtin_fmaf(dt, dV, V);
                    const bool  s  = (Vr >= V_spike);
                    (o + (size_t)k * Dn)[dd] = s ? 1.0f : 0.0f;
                    const float xn = (Vr - V_T) * rDT;          // speculative
                    V   = s ? V_reset : Vr;
                    x   = s ? xC : xn;
                    nEL = E_L - V;   // direct; == s?(E_L-Vrst):(E_L-Vr) bitwise
                }
            }
            if (tb + 2 < NB) {
                const float* p = IpU + (size_t)(tb + 2) * (UNR * Dn);
                #pragma unroll
                for (int k = 0; k < UNR; ++k) bufA[k] = (p + (size_t)k * Dn)[dd];
            }
            if (tb + 1 < NB) {
                float* o = OpU + (size_t)(tb + 1) * (UNR * Dn);
                #pragma unroll
                for (int k = 0; k < UNR; ++k) {
                    const float et = expsc(x, kdt);
                    float nm = nEL + et;
                    nm = nm + bufB[k];
                    const float dV = div_uniform(nm, tau_m, rTM);
                    const float Vr = __builtin_fmaf(dt, dV, V);
                    const bool  s  = (Vr >= V_spike);
                    (o + (size_t)k * Dn)[dd] = s ? 1.0f : 0.0f;
                    const float xn = (Vr - V_T) * rDT;
                    V   = s ? V_reset : Vr;
                    x   = s ? xC : xn;
                    nEL = E_L - V;
                }
            }
        }
        return;
    }

    // -------- fallback paths (R3-proven) --------
    const bool simple = (a == 0.0f) && (b == 0.0f);

    if (simple) {
        for (int tb = 0; tb < NB; tb += 2) {
            if (tb + 1 < NB) {
                const float* p = IpU + (size_t)(tb + 1) * (UNR * Dn);
                #pragma unroll
                for (int k = 0; k < UNR; ++k) bufB[k] = (p + (size_t)k * Dn)[dd];
            }
            {
                float* o = OpU + (size_t)tb * (UNR * Dn);
                #pragma unroll
                for (int k = 0; k < UNR; ++k) {
                    float spk;
                    step_simple(V, bufA[k], spk, E_L, V_T, Delta_T, R, tau_m,
                                V_spike, V_reset, dt);
                    (o + (size_t)k * Dn)[dd] = spk;
                }
            }
            if (tb + 2 < NB) {
                const float* p = IpU + (size_t)(tb + 2) * (UNR * Dn);
                #pragma unroll
                for (int k = 0; k < UNR; ++k) bufA[k] = (p + (size_t)k * Dn)[dd];
            }
            if (tb + 1 < NB) {
                float* o = OpU + (size_t)(tb + 1) * (UNR * Dn);
                #pragma unroll
                for (int k = 0; k < UNR; ++k) {
                    float spk;
                    step_simple(V, bufB[k], spk, E_L, V_T, Delta_T, R, tau_m,
                                V_spike, V_reset, dt);
                    (o + (size_t)k * Dn)[dd] = spk;
                }
            }
        }
    } else {
        float w = 0.0f;
        for (int tb = 0; tb < NB; tb += 2) {
            if (tb + 1 < NB) {
                const float* p = IpU + (size_t)(tb + 1) * (UNR * Dn);
                #pragma unroll
                for (int k = 0; k < UNR; ++k) bufB[k] = (p + (size_t)k * Dn)[dd];
            }
            {
                float* o = OpU + (size_t)tb * (UNR * Dn);
                #pragma unroll
                for (int k = 0; k < UNR; ++k) {
                    float spk;
                    step_general(V, w, bufA[k], spk, E_L, V_T, Delta_T, R, tau_m,
                                 tau_w, a, b, V_spike, V_reset, dt);
                    (o + (size_t)k * Dn)[dd] = spk;
                }
            }
            if (tb + 2 < NB) {
                const float* p = IpU + (size_t)(tb + 2) * (UNR * Dn);
                #pragma unroll
                for (int k = 0; k < UNR; ++k) bufA[k] = (p + (size_t)k * Dn)[dd];
            }
            if (tb + 1 < NB) {
                float* o = OpU + (size_t)(tb + 1) * (UNR * Dn);
                #pragma unroll
                for (int k = 0; k < UNR; ++k) {
                    float spk;
                    step_general(V, w, bufB[k], spk, E_L, V_T, Delta_T, R, tau_m,
                                 tau_w, a, b, V_spike, V_reset, dt);
                    (o + (size_t)k * Dn)[dd] = spk;
                }
            }
        }
    }
}

extern "C" void kernel_launch(void* const* d_in, const int* in_sizes, int n_in,
                              void* d_out, int out_size, void* d_ws, size_t ws_size,
                              hipStream_t stream) {
    const float* I      = (const float*)d_in[0];
    const float* params = (const float*)d_in[1];
    float*       out    = (float*)d_out;

    dim3 block(128);
    dim3 grid(NEUR / 128);  // 256 blocks -> 1 per CU
    adex_kernel<<<grid, block, 0, stream>>>(I, params, out);
}

// Round 10
// 179.104 us; speedup vs baseline: 1.1632x; 1.0349x over previous
//
#include <hip/hip_runtime.h>

// AdEx neuron simulation: B=32, T=2000, D=1024. Bitwise-exact vs JAX/XLA:CPU
// (numerics proven R3/R4/R9: XLA Cephes exp + FMA-contracted step, absmax 0.0).
//
// R10 = true spine cuts (21 -> 19 carried edges), both bitwise-proven via
// "RN commutes with exact power-of-2 scaling":
//  (1) xn = fma(Vr, rDT, -VTdt)  ==  (Vr - V_T) * rDT   [rDT pow2, VTdt exact]
//  (2) et = fma(y, sc, sc)       ==  (y + 1) * sc       [sc = 2^(n+kdt) pow2]
// Model under test: 1 spine edge ~ 11 cyc/step ~ 9 us (R6 was a reorder, not
// a cut -> its neutrality doesn't refute the model). SADDR block-uniform
// addressing + direct nEL (R9, -2 us) retained. Fallbacks R3-proven intact.

#define Bn 32
#define Tn 2000
#define Dn 1024
#define NEUR (Bn * Dn)     // 32768
#define UNR 16             // prefetch depth (2000 % 16 == 0 -> NB = 125)
#define NB (Tn / UNR)

// ---------- exp: XLA:CPU / Eigen Cephes, FMA-contracted (R3-proven) ----------
#define EXP_LOG2EF 1.44269504088896341f
#define EXP_C1 0.693359375f
#define EXP_C2 -2.12194440e-4f
#define EXP_P0 1.9875691500e-4f
#define EXP_P1 1.3981999507e-3f
#define EXP_P2 8.3334519073e-3f
#define EXP_P3 4.1665795894e-2f
#define EXP_P4 1.6666665459e-1f
#define EXP_P5 5.0000001201e-1f

__device__ __forceinline__ float ref_expf(float x) {
    #pragma clang fp contract(off)
    float fx = __builtin_floorf(__builtin_fmaf(x, EXP_LOG2EF, 0.5f));
    float xr = __builtin_fmaf(fx, -EXP_C1, x);
    xr = __builtin_fmaf(fx, -EXP_C2, xr);
    float z2 = xr * xr;
    float y = EXP_P0;
    y = __builtin_fmaf(y, xr, EXP_P1);
    y = __builtin_fmaf(y, xr, EXP_P2);
    y = __builtin_fmaf(y, xr, EXP_P3);
    y = __builtin_fmaf(y, xr, EXP_P4);
    y = __builtin_fmaf(y, xr, EXP_P5);
    y = __builtin_fmaf(y, z2, xr);
    y = y + 1.0f;
    const int n = (int)fx;
    return y * __int_as_float((n + 127) << 23);
}

// Markstein correctly-rounded division by loop-invariant d, r = RN(1/d).
__device__ __forceinline__ float div_uniform(float x, float d, float r) {
    #pragma clang fp contract(off)
    float q = x * r;
    float e = __builtin_fmaf(-d, q, x);
    return __builtin_fmaf(e, r, q);
}

// ---------- R3-proven fallback steps (plain IEEE divides) ----------
__device__ __forceinline__ void step_simple(float& V, float i_t, float& spk_out,
                                            float E_L, float V_T, float Delta_T,
                                            float R, float tau_m, float V_spike,
                                            float V_reset, float dt) {
    #pragma clang fp contract(off)
    const float e  = ref_expf((V - V_T) / Delta_T);
    const float et = Delta_T * e;
    float nm = (-(V - E_L) + et);
    nm = nm + R * i_t;
    const float dV = nm / tau_m;
    V = __builtin_fmaf(dt, dV, V);
    spk_out = (V >= V_spike) ? 1.0f : 0.0f;
    V = (V >= V_spike) ? V_reset : V;
}

__device__ __forceinline__ void step_general(float& V, float& w, float i_t, float& spk_out,
                                             float E_L, float V_T, float Delta_T,
                                             float R, float tau_m, float tau_w,
                                             float a, float b,
                                             float V_spike, float V_reset, float dt) {
    #pragma clang fp contract(off)
    const float e  = ref_expf((V - V_T) / Delta_T);
    const float et = Delta_T * e;
    float nm = (-(V - E_L) + et);
    nm = __builtin_fmaf(-R, w, nm);
    nm = __builtin_fmaf(R, i_t, nm);
    const float dV = nm / tau_m;
    V = __builtin_fmaf(dt, dV, V);
    const float dwn = __builtin_fmaf(a, (V - E_L), -w);
    const float dw  = dwn / tau_w;
    w = __builtin_fmaf(dt, dw, w);
    spk_out = (V >= V_spike) ? 1.0f : 0.0f;
    const bool s = (V >= V_spike);
    V = s ? V_reset : V;
    w = s ? (w + b) : w;
}

__launch_bounds__(128, 1)
__global__ void adex_kernel(const float* __restrict__ I,
                            const float* __restrict__ params,
                            float* __restrict__ out) {
    #pragma clang fp contract(off)

    const float tau_m   = params[0];
    const float E_L     = params[1];
    const float V_T     = params[2];
    const float Delta_T = params[3];
    const float R       = params[4];
    const float tau_w   = params[5];
    const float a       = params[6];
    const float b       = params[7];
    const float V_reset = params[8];
    const float V_spike = params[9];
    const float dt      = params[10];

    // Block-uniform batch index (SGPR), per-lane column index (VGPR). (R9)
    const int bb = (int)(blockIdx.x >> 3);                         // uniform
    const int dd = (int)((blockIdx.x & 7) * 128 + threadIdx.x);    // varying

    const float* IpU = I   + (size_t)bb * (size_t)(Tn * Dn);
    float*       OpU = out + (size_t)bb * (size_t)(Tn * Dn);

    float V = E_L;
    float bufA[UNR], bufB[UNR];

    #pragma unroll
    for (int k = 0; k < UNR; ++k) bufA[k] = (IpU + (size_t)k * Dn)[dd];

    const unsigned dtBits = __float_as_uint(Delta_T);
    const bool dtPow2 = ((dtBits & 0x7FFFFFu) == 0u) && Delta_T > 0.0f;
    const bool hot = (a == 0.0f) && (b == 0.0f) && (R == 1.0f) && dtPow2;

    if (hot) {
        // -------- latency-optimized path --------
        const int   kdt  = (int)((dtBits >> 23) & 0xFFu) - 127;  // log2(Delta_T)
        const float rDT  = 1.0f / Delta_T;                        // exact (pow2)
        const float rTM  = 1.0f / tau_m;                          // RN(1/tau_m)
        const float mVTdt = -(V_T * rDT);                         // exact (pow2 scale)
        const float xC   = (V_reset - V_T) * rDT;                 // reset-branch x

        float x   = (V - V_T) * rDT;   // == (V-V_T)/Delta_T bitwise
        float nEL = E_L - V;           // == -(V-E_L) bitwise

        // One hot step; spine (19 edges): fma,floor,2xr,5poly,merge,
        // et-fma, +nEL, +i, 3-div, V-fma, xn-fma, cnd.
        #define HOT_STEP(i_t, OSL) do {                                           \
            const float fx = __builtin_floorf(__builtin_fmaf(x, EXP_LOG2EF, 0.5f)); \
            float xr = __builtin_fmaf(fx, -EXP_C1, x);                            \
            xr = __builtin_fmaf(fx, -EXP_C2, xr);                                 \
            const float z2 = xr * xr;                                             \
            float y = __builtin_fmaf(EXP_P0, xr, EXP_P1);                         \
            y = __builtin_fmaf(y, xr, EXP_P2);                                    \
            y = __builtin_fmaf(y, xr, EXP_P3);                                    \
            y = __builtin_fmaf(y, xr, EXP_P4);                                    \
            y = __builtin_fmaf(y, xr, EXP_P5);                                    \
            y = __builtin_fmaf(y, z2, xr);                                        \
            const int   nsc = (int)fx;                                            \
            const float sc  = __int_as_float((nsc + 127 + kdt) << 23);            \
            const float et  = __builtin_fmaf(y, sc, sc);  /* ==(y+1)*sc, pow2 */  \
            float nm = nEL + et;                                                  \
            nm = nm + (i_t);                              /* R == 1 */            \
            const float q  = nm * rTM;                                            \
            const float er = __builtin_fmaf(-tau_m, q, nm);                       \
            const float dV = __builtin_fmaf(er, rTM, q);                          \
            const float Vr = __builtin_fmaf(dt, dV, V);                           \
            const bool  s  = (Vr >= V_spike);                                     \
            (OSL) = s ? 1.0f : 0.0f;                                              \
            const float xn = __builtin_fmaf(Vr, rDT, mVTdt); /* ==(Vr-V_T)*rDT */ \
            V   = s ? V_reset : Vr;                                               \
            x   = s ? xC : xn;                                                    \
            nEL = E_L - V;                                /* R9: direct */        \
        } while (0)

        for (int tb = 0; tb < NB; tb += 2) {
            if (tb + 1 < NB) {
                const float* p = IpU + (size_t)(tb + 1) * (UNR * Dn);
                #pragma unroll
                for (int k = 0; k < UNR; ++k) bufB[k] = (p + (size_t)k * Dn)[dd];
            }
            {
                float* o = OpU + (size_t)tb * (UNR * Dn);
                #pragma unroll
                for (int k = 0; k < UNR; ++k) HOT_STEP(bufA[k], (o + (size_t)k * Dn)[dd]);
            }
            if (tb + 2 < NB) {
                const float* p = IpU + (size_t)(tb + 2) * (UNR * Dn);
                #pragma unroll
                for (int k = 0; k < UNR; ++k) bufA[k] = (p + (size_t)k * Dn)[dd];
            }
            if (tb + 1 < NB) {
                float* o = OpU + (size_t)(tb + 1) * (UNR * Dn);
                #pragma unroll
                for (int k = 0; k < UNR; ++k) HOT_STEP(bufB[k], (o + (size_t)k * Dn)[dd]);
            }
        }
        #undef HOT_STEP
        return;
    }

    // -------- fallback paths (R3-proven) --------
    const bool simple = (a == 0.0f) && (b == 0.0f);

    if (simple) {
        for (int tb = 0; tb < NB; tb += 2) {
            if (tb + 1 < NB) {
                const float* p = IpU + (size_t)(tb + 1) * (UNR * Dn);
                #pragma unroll
                for (int k = 0; k < UNR; ++k) bufB[k] = (p + (size_t)k * Dn)[dd];
            }
            {
                float* o = OpU + (size_t)tb * (UNR * Dn);
                #pragma unroll
                for (int k = 0; k < UNR; ++k) {
                    float spk;
                    step_simple(V, bufA[k], spk, E_L, V_T, Delta_T, R, tau_m,
                                V_spike, V_reset, dt);
                    (o + (size_t)k * Dn)[dd] = spk;
                }
            }
            if (tb + 2 < NB) {
                const float* p = IpU + (size_t)(tb + 2) * (UNR * Dn);
                #pragma unroll
                for (int k = 0; k < UNR; ++k) bufA[k] = (p + (size_t)k * Dn)[dd];
            }
            if (tb + 1 < NB) {
                float* o = OpU + (size_t)(tb + 1) * (UNR * Dn);
                #pragma unroll
                for (int k = 0; k < UNR; ++k) {
                    float spk;
                    step_simple(V, bufB[k], spk, E_L, V_T, Delta_T, R, tau_m,
                                V_spike, V_reset, dt);
                    (o + (size_t)k * Dn)[dd] = spk;
                }
            }
        }
    } else {
        float w = 0.0f;
        for (int tb = 0; tb < NB; tb += 2) {
            if (tb + 1 < NB) {
                const float* p = IpU + (size_t)(tb + 1) * (UNR * Dn);
                #pragma unroll
                for (int k = 0; k < UNR; ++k) bufB[k] = (p + (size_t)k * Dn)[dd];
            }
            {
                float* o = OpU + (size_t)tb * (UNR * Dn);
                #pragma unroll
                for (int k = 0; k < UNR; ++k) {
                    float spk;
                    step_general(V, w, bufA[k], spk, E_L, V_T, Delta_T, R, tau_m,
                                 tau_w, a, b, V_spike, V_reset, dt);
                    (o + (size_t)k * Dn)[dd] = spk;
                }
            }
            if (tb + 2 < NB) {
                const float* p = IpU + (size_t)(tb + 2) * (UNR * Dn);
                #pragma unroll
                for (int k = 0; k < UNR; ++k) bufA[k] = (p + (size_t)k * Dn)[dd];
            }
            if (tb + 1 < NB) {
                float* o = OpU + (size_t)(tb + 1) * (UNR * Dn);
                #pragma unroll
                for (int k = 0; k < UNR; ++k) {
                    float spk;
                    step_general(V, w, bufB[k], spk, E_L, V_T, Delta_T, R, tau_m,
                                 tau_w, a, b, V_spike, V_reset, dt);
                    (o + (size_t)k * Dn)[dd] = spk;
                }
            }
        }
    }
}

extern "C" void kernel_launch(void* const* d_in, const int* in_sizes, int n_in,
                              void* d_out, int out_size, void* d_ws, size_t ws_size,
                              hipStream_t stream) {
    const float* I      = (const float*)d_in[0];
    const float* params = (const float*)d_in[1];
    float*       out    = (float*)d_out;

    dim3 block(128);
    dim3 grid(NEUR / 128);  // 256 blocks -> 1 per CU
    adex_kernel<<<grid, block, 0, stream>>>(I, params, out);
}